// Round 4
// baseline (273.568 us; speedup 1.0000x reference)
//
#include <hip/hip_runtime.h>
#include <math.h>

#define BB 8
#define TT 100
#define PP 1000
#define NJ 52     // padded j count in V regs (50 real)
#define GROW 56   // G row stride floats (224B, 16B aligned)
#define HSTRIDE 68 // h_all row stride floats (272B, 16B aligned; bank shift 4/row)

// ws layout (floats):
//   xk : [800][256] at 0        (204800)
//   XcT: [56][1000] at 204800   (56000)
//   G  : [800][56]  at 260800   (44800)

// ---------------- PREP: blocks 0..99 = k1 (xk), blocks 100..115 = k3 (XcT) ------------
__global__ __launch_bounds__(256) void prep(const int* __restrict__ pro_id,
    const int* __restrict__ label, const float* __restrict__ X,
    const float* __restrict__ onehot, const float* __restrict__ kern,
    const float* __restrict__ bias, const float* __restrict__ W1,
    const float* __restrict__ b1, float* __restrict__ xk, float* __restrict__ XcT)
{
    __shared__ __align__(16) float smem[128 * 65];  // 33.3 KB (max of both paths)
    const int tid = threadIdx.x;

    if (blockIdx.x < 100) {
        // ---- k1: xk[bt][j] = bias[j] + sum_k xt[bt][k]*kernel[k][j] ----
        float (*xt)[256] = (float(*)[256])smem;
        const int j = tid;
        const int r0 = blockIdx.x * 8;
        for (int r = 0; r < 8; ++r) {
            int row = r0 + r;
            int pid = pro_id[row];
            int lab = label[row];
            xt[r][j] = X[pid * 128 + (j & 127)] * onehot[lab * 256 + j];
        }
        __syncthreads();
        float acc[8];
        float bj = bias[j];
#pragma unroll
        for (int r = 0; r < 8; ++r) acc[r] = bj;
        for (int k4 = 0; k4 < 256; k4 += 4) {
            float4 xv[8];
#pragma unroll
            for (int r = 0; r < 8; ++r) xv[r] = *(const float4*)&xt[r][k4];
#pragma unroll
            for (int kk = 0; kk < 4; ++kk) {
                float kv = kern[(k4 + kk) * 256 + j];
#pragma unroll
                for (int r = 0; r < 8; ++r) {
                    float x = (kk == 0) ? xv[r].x : (kk == 1) ? xv[r].y : (kk == 2) ? xv[r].z : xv[r].w;
                    acc[r] += x * kv;
                }
            }
        }
#pragma unroll
        for (int r = 0; r < 8; ++r) xk[(r0 + r) * 256 + j] = acc[r];
    } else {
        // ---- k3: XcT[j][p] = b1[j] + sum_k X[p][k]*W1[64+k][j] ----
        // Stage X transposed in LDS: Xs[k][i] = X[p0+i][k], stride 65 (conflict-free reads)
        const int p0 = (blockIdx.x - 100) * 64;
#pragma unroll
        for (int r = 0; r < 8; ++r) {
            int flat = (tid + 256 * r) * 4;
            int i = flat >> 7;          // 0..63
            int k = flat & 127;
            int p = p0 + i;
            float4 v = make_float4(0.f, 0.f, 0.f, 0.f);
            if (p < PP) v = *(const float4*)&X[p * 128 + k];
            smem[(k + 0) * 65 + i] = v.x;
            smem[(k + 1) * 65 + i] = v.y;
            smem[(k + 2) * 65 + i] = v.z;
            smem[(k + 3) * 65 + i] = v.w;
        }
        __syncthreads();
        const int ploc = tid & 63;
        const int j0 = tid >> 6;        // wave-uniform -> W1 scalar loads
        float acc[13];
#pragma unroll
        for (int m = 0; m < 13; ++m) {
            int j = j0 + 4 * m;
            acc[m] = (j < 50) ? b1[j] : 0.f;
        }
        for (int k = 0; k < 128; ++k) {
            float xv = smem[k * 65 + ploc];
            const float* w1r = &W1[(64 + k) * 50];
#pragma unroll
            for (int m = 0; m < 13; ++m) {
                int j = j0 + 4 * m;
                if (j < 50) acc[m] += xv * w1r[j];
            }
        }
        int p = p0 + ploc;
        if (p < PP) {
#pragma unroll
            for (int m = 0; m < 13; ++m) {
                int j = j0 + 4 * m;
                if (j < 50) XcT[j * PP + p] = acc[m];
            }
        }
        // zero pad rows 50..55
        for (int idx = tid; idx < 6 * 64; idx += 256) {
            int r = 50 + (idx >> 6);
            int pp = p0 + (idx & 63);
            if (pp < PP) XcT[r * PP + pp] = 0.f;
        }
    }
}

// ---------------- K2 v2: LSTM, 1 block/batch, gate-interleaved lanes, 1 barrier/step ---
// lane l, wave w: unit u = (w<<4)|(l&15), gate g = l>>4, z-column = g*64+u.
// h history in LDS rows (read row t, write row t+1 -> no WAR, single barrier).
// G tail fused (h already in LDS).
__global__ __launch_bounds__(256) void k2_lstm(const float* __restrict__ xk,
    const float* __restrict__ rec, const float* __restrict__ W1,
    float* __restrict__ G)
{
    __shared__ __align__(16) float h_all[(TT + 1) * HSTRIDE];  // 27.5 KB
    const int tid = threadIdx.x;
    const int b = blockIdx.x;
    const int l = tid & 63;
    const int w = tid >> 6;
    const int u = (w << 4) | (l & 15);
    const int g = l >> 4;
    const int col = (g << 6) | u;

    float rcol[64];
#pragma unroll
    for (int u2 = 0; u2 < 64; ++u2) rcol[u2] = rec[u2 * 256 + col];

    if (tid < 64) h_all[tid] = 0.f;  // row 0 = h(-1) = 0
    float c = 0.f;
    const float* xkb = xk + b * TT * 256;
    float zc = xkb[col];             // prefetch t=0
    __syncthreads();

    for (int t = 0; t < TT; ++t) {
        float a0 = zc, a1 = 0.f, a2 = 0.f, a3 = 0.f;
        if (t < TT - 1) zc = xkb[(t + 1) * 256 + col];  // prefetch next step
        const float4* h4p = (const float4*)&h_all[t * HSTRIDE];
#pragma unroll
        for (int m = 0; m < 16; ++m) {
            float4 hv = h4p[m];      // broadcast read, conflict-free
            a0 += hv.x * rcol[4 * m + 0];
            a1 += hv.y * rcol[4 * m + 1];
            a2 += hv.z * rcol[4 * m + 2];
            a3 += hv.w * rcol[4 * m + 3];
        }
        float z = (a0 + a1) + (a2 + a3);
        float act;
        if (g == 2) act = 2.f / (1.f + __expf(-2.f * z)) - 1.f;   // tanh gate
        else        act = 1.f / (1.f + __expf(-z));                // sigmoid gates
        const int base = l & 15;
        float gi = __shfl(act, base);
        float gf = __shfl(act, base + 16);
        float gg = __shfl(act, base + 32);
        float go = __shfl(act, base + 48);
        c = gf * c + gi * gg;
        float h = go * (2.f / (1.f + __expf(-2.f * c)) - 1.f);
        if (g == 0) h_all[(t + 1) * HSTRIDE + u] = h;
        __syncthreads();
    }

    // ---- fused G tail: G[b*100+row][j] = sum_u h_all[row+1][u] * W1[u][j] ----
    const int brow0 = b * TT;
    for (int idx = tid; idx < TT * 13; idx += 256) {
        int row = idx / 13;
        int m = idx - row * 13;
        int j = 4 * m;                       // 0..48
        const float* hrow = &h_all[(row + 1) * HSTRIDE];
        float ax = 0.f, ay = 0.f, az = 0.f, aw = 0.f;
#pragma unroll 16
        for (int u2 = 0; u2 < 64; ++u2) {
            float hv = hrow[u2];
            const float* wp = &W1[u2 * 50 + j];
            ax += hv * wp[0];
            ay += hv * wp[1];
            az += hv * wp[2];                // j=48: reads next row, zeroed below
            aw += hv * wp[3];
        }
        if (m == 12) { az = 0.f; aw = 0.f; } // cols 50,51 = 0
        float4 o = make_float4(ax, ay, az, aw);
        *(float4*)&G[(brow0 + row) * GROW + j] = o;
    }
}

// ---------------- K4: suffix-accumulate V[p,j] += a[s,p]*G[s,j]; emit per t-chunk ------
__global__ __launch_bounds__(256) void k4_main(const int* __restrict__ pro_id,
    const float* __restrict__ cos_X, const float* __restrict__ XcT,
    const float* __restrict__ G, const float* __restrict__ W2,
    const float* __restrict__ b2, float* __restrict__ out)
{
    const int b = blockIdx.z;
    const int p = blockIdx.y * 256 + threadIdx.x;
    const int ci = blockIdx.x;
    const int t0 = ci * 7;
    const int t1 = (t0 + 7 < TT) ? (t0 + 7) : TT;
    const bool valid = p < PP;
    const int pc = valid ? p : 0;

    float V[NJ];
#pragma unroll
    for (int jj = 0; jj < NJ; ++jj) V[jj] = XcT[jj * PP + pc];
    const float b2v = b2[0];

    for (int s = TT - 1; s >= t0; --s) {
        int pid = pro_id[b * TT + s];
        float a = cos_X[pid * PP + pc];
        const float4* G4 = (const float4*)(G + (b * TT + s) * GROW);
#pragma unroll
        for (int jv = 0; jv < 13; ++jv) {
            float4 gv = G4[jv];
            V[4 * jv + 0] += a * gv.x;
            V[4 * jv + 1] += a * gv.y;
            V[4 * jv + 2] += a * gv.z;
            V[4 * jv + 3] += a * gv.w;
        }
        if (s < t1) {
            float acc = b2v;
#pragma unroll
            for (int jv = 0; jv < 12; ++jv) {
                float4 wv = *(const float4*)&W2[4 * jv];
                acc += wv.x * fmaxf(V[4 * jv + 0], 0.f)
                     + wv.y * fmaxf(V[4 * jv + 1], 0.f)
                     + wv.z * fmaxf(V[4 * jv + 2], 0.f)
                     + wv.w * fmaxf(V[4 * jv + 3], 0.f);
            }
            acc += W2[48] * fmaxf(V[48], 0.f) + W2[49] * fmaxf(V[49], 0.f);
            if (valid) out[(b * TT + s) * PP + p] = acc;
        }
    }
}

extern "C" void kernel_launch(void* const* d_in, const int* in_sizes, int n_in,
                              void* d_out, int out_size, void* d_ws, size_t ws_size,
                              hipStream_t stream)
{
    const int* pro_id  = (const int*)d_in[0];
    const int* label   = (const int*)d_in[1];
    const float* X     = (const float*)d_in[3];
    const float* cos_X = (const float*)d_in[4];
    // d_in[5] trimatrix: structurally tril(ones) — suffix-sum semantics hardcoded
    const float* onehot = (const float*)d_in[6];
    const float* lk    = (const float*)d_in[7];
    const float* lr    = (const float*)d_in[8];
    const float* lb    = (const float*)d_in[9];
    const float* W1    = (const float*)d_in[10];
    const float* b1    = (const float*)d_in[11];
    const float* W2    = (const float*)d_in[12];
    const float* b2    = (const float*)d_in[13];

    float* ws  = (float*)d_ws;
    float* xk  = ws;            // 204800
    float* XcT = ws + 204800;   // 56000
    float* G   = ws + 260800;   // 44800
    float* out = (float*)d_out;

    hipLaunchKernelGGL(prep,   dim3(116),      dim3(256), 0, stream,
                       pro_id, label, X, onehot, lk, lb, W1, b1, xk, XcT);
    hipLaunchKernelGGL(k2_lstm,dim3(8),        dim3(256), 0, stream, xk, lr, W1, G);
    hipLaunchKernelGGL(k4_main,dim3(15, 4, 8), dim3(256), 0, stream,
                       pro_id, cos_X, XcT, G, W2, b2, out);
}

// Round 5
// 264.616 us; speedup vs baseline: 1.0338x; 1.0338x over previous
//
#include <hip/hip_runtime.h>
#include <math.h>

#define BB 8
#define TT 100
#define PP 1000
#define NJ 52      // V regs per thread in k4 (50 real j, 2 pad)
#define GROW 56    // G row stride floats (224B, 16B aligned)
#define HSTRIDE 68 // h_all row stride floats (272B, 16B aligned)

// ws layout (floats):
//   xk : [800][256] at 0        (204800)
//   XcT: [56][1000] at 204800   (56000)
//   G  : [800][56]  at 260800   (44800)

// ---------------- PREP: blocks 0..99 = k1 (xk), blocks 100..115 = k3 (XcT) ------------
// k1: LDS-staged kern chunks (32 k-rows), double-buffered via 8 independent float4
//     register loads -> no per-iteration vmcnt(0) stall (round-4 prep was 85us, 2% VALU).
// k3: X staged transposed + W1c staged as W1T[j][k] -> all inner-loop operands in LDS.
__global__ __launch_bounds__(256) void prep(const int* __restrict__ pro_id,
    const int* __restrict__ label, const float* __restrict__ X,
    const float* __restrict__ onehot, const float* __restrict__ kern,
    const float* __restrict__ bias, const float* __restrict__ W1,
    const float* __restrict__ b1, float* __restrict__ xk, float* __restrict__ XcT)
{
    __shared__ __align__(16) float smem[18432];  // 73.7 KB (union of both paths)
    const int tid = threadIdx.x;

    if (blockIdx.x < 100) {
        // ---- k1: xk[bt][j] = bias[j] + sum_k xt[bt][k]*kernel[k][j], 8 rows/block ----
        float* kb0 = smem;                    // [32][256]
        float* kb1 = smem + 8192;             // [32][256]
        float (*xt)[256] = (float(*)[256])(smem + 16384);  // [8][256]
        const int j = tid;
        const int r0 = blockIdx.x * 8;
        int pids[8], labs[8];
#pragma unroll
        for (int r = 0; r < 8; ++r) { pids[r] = pro_id[r0 + r]; labs[r] = label[r0 + r]; }
#pragma unroll
        for (int r = 0; r < 8; ++r)
            xt[r][j] = X[pids[r] * 128 + (j & 127)] * onehot[labs[r] * 256 + j];

        const float4* kern4 = (const float4*)kern;
        float4 kreg[8];
#pragma unroll
        for (int i = 0; i < 8; ++i) kreg[i] = kern4[tid + 256 * i];   // chunk 0
        {
            float4* dst = (float4*)kb0;
#pragma unroll
            for (int i = 0; i < 8; ++i) dst[tid + 256 * i] = kreg[i];
        }
        __syncthreads();

        float acc[8];
        float bj = bias[j];
#pragma unroll
        for (int r = 0; r < 8; ++r) acc[r] = bj;

        for (int c = 0; c < 8; ++c) {
            const float* kb = (c & 1) ? kb1 : kb0;
            if (c < 7) {
#pragma unroll
                for (int i = 0; i < 8; ++i)
                    kreg[i] = kern4[(c + 1) * 2048 + tid + 256 * i];  // prefetch next chunk
            }
#pragma unroll
            for (int kk4 = 0; kk4 < 8; ++kk4) {
                const int k = c * 32 + kk4 * 4;
                float kv0 = kb[(kk4 * 4 + 0) * 256 + j];
                float kv1 = kb[(kk4 * 4 + 1) * 256 + j];
                float kv2 = kb[(kk4 * 4 + 2) * 256 + j];
                float kv3 = kb[(kk4 * 4 + 3) * 256 + j];
#pragma unroll
                for (int r = 0; r < 8; ++r) {
                    float4 xv = *(const float4*)&xt[r][k];   // lane-uniform broadcast
                    acc[r] += xv.x * kv0 + xv.y * kv1 + xv.z * kv2 + xv.w * kv3;
                }
            }
            __syncthreads();
            if (c < 7) {
                float4* dst = (float4*)((c & 1) ? kb0 : kb1);
#pragma unroll
                for (int i = 0; i < 8; ++i) dst[tid + 256 * i] = kreg[i];
                __syncthreads();
            }
        }
#pragma unroll
        for (int r = 0; r < 8; ++r) xk[(r0 + r) * 256 + j] = acc[r];
    } else {
        // ---- k3: XcT[j][p] = b1[j] + sum_k X[p][k]*W1[64+k][j] ----
        float* Xs  = smem;          // [128][65]
        float* W1T = smem + 8320;   // [50][128]
        const int p0 = (blockIdx.x - 100) * 64;
        for (int idx = tid; idx < 6400; idx += 256) {
            int k = idx & 127, jj = idx >> 7;
            W1T[jj * 128 + k] = W1[(64 + k) * 50 + jj];
        }
#pragma unroll
        for (int r = 0; r < 8; ++r) {
            int flat = (tid + 256 * r) * 4;
            int i = flat >> 7;
            int k = flat & 127;
            int p = p0 + i;
            float4 v = make_float4(0.f, 0.f, 0.f, 0.f);
            if (p < PP) v = *(const float4*)&X[p * 128 + k];
            Xs[(k + 0) * 65 + i] = v.x;
            Xs[(k + 1) * 65 + i] = v.y;
            Xs[(k + 2) * 65 + i] = v.z;
            Xs[(k + 3) * 65 + i] = v.w;
        }
        __syncthreads();
        const int ploc = tid & 63;
        const int j0 = tid >> 6;          // 0..3, wave-uniform
        float acc[13];
#pragma unroll
        for (int m = 0; m < 13; ++m) {
            int jj = j0 * 13 + m;
            acc[m] = (jj < 50) ? b1[jj] : 0.f;
        }
        for (int k4 = 0; k4 < 32; ++k4) {
            const int k = 4 * k4;
            float x0 = Xs[(k + 0) * 65 + ploc];
            float x1 = Xs[(k + 1) * 65 + ploc];
            float x2 = Xs[(k + 2) * 65 + ploc];
            float x3 = Xs[(k + 3) * 65 + ploc];
#pragma unroll
            for (int m = 0; m < 13; ++m) {
                int jj = j0 * 13 + m;
                if (jj < 50) {
                    float4 w = *(const float4*)&W1T[jj * 128 + k];  // broadcast b128
                    acc[m] += x0 * w.x + x1 * w.y + x2 * w.z + x3 * w.w;
                }
            }
        }
        int p = p0 + ploc;
        if (p < PP) {
#pragma unroll
            for (int m = 0; m < 13; ++m) {
                int jj = j0 * 13 + m;
                if (jj < 50) XcT[jj * PP + p] = acc[m];
            }
        }
        for (int idx = tid; idx < 6 * 64; idx += 256) {
            int r = 50 + (idx >> 6);
            int pp = p0 + (idx & 63);
            if (pp < PP) XcT[r * PP + pp] = 0.f;
        }
    }
}

// ---------------- K2: LSTM, 1 block/batch, gate-interleaved lanes, 1 barrier/step ------
// G tail fused, W1 staged in LDS (round-4 tail did per-thread scattered global W1 reads).
__global__ __launch_bounds__(256) void k2_lstm(const float* __restrict__ xk,
    const float* __restrict__ rec, const float* __restrict__ W1,
    float* __restrict__ G)
{
    __shared__ __align__(16) float h_all[(TT + 1) * HSTRIDE];  // 27.5 KB
    __shared__ __align__(16) float w1s[64 * 52];               // 13.3 KB, [u][52]
    const int tid = threadIdx.x;
    const int b = blockIdx.x;
    const int l = tid & 63;
    const int w = tid >> 6;
    const int u = (w << 4) | (l & 15);
    const int g = l >> 4;
    const int col = (g << 6) | u;

    for (int idx = tid; idx < 3200; idx += 256) {
        int u2 = idx / 50, jj = idx - u2 * 50;
        w1s[u2 * 52 + jj] = W1[idx];
    }
    float rcol[64];
#pragma unroll
    for (int u2 = 0; u2 < 64; ++u2) rcol[u2] = rec[u2 * 256 + col];

    if (tid < 64) h_all[tid] = 0.f;  // row 0 = h(-1)
    float c = 0.f;
    const float* xkb = xk + b * TT * 256;
    float zc = xkb[col];             // prefetch t=0
    __syncthreads();

    for (int t = 0; t < TT; ++t) {
        float a0 = zc, a1 = 0.f, a2 = 0.f, a3 = 0.f;
        if (t < TT - 1) zc = xkb[(t + 1) * 256 + col];
        const float4* h4p = (const float4*)&h_all[t * HSTRIDE];
#pragma unroll
        for (int m = 0; m < 16; ++m) {
            float4 hv = h4p[m];      // broadcast
            a0 += hv.x * rcol[4 * m + 0];
            a1 += hv.y * rcol[4 * m + 1];
            a2 += hv.z * rcol[4 * m + 2];
            a3 += hv.w * rcol[4 * m + 3];
        }
        float z = (a0 + a1) + (a2 + a3);
        float act;
        if (g == 2) act = 2.f / (1.f + __expf(-2.f * z)) - 1.f;   // tanh gate
        else        act = 1.f / (1.f + __expf(-z));
        const int base = l & 15;
        float gi = __shfl(act, base);
        float gf = __shfl(act, base + 16);
        float gg = __shfl(act, base + 32);
        float go = __shfl(act, base + 48);
        c = gf * c + gi * gg;
        float h = go * (2.f / (1.f + __expf(-2.f * c)) - 1.f);
        if (g == 0) h_all[(t + 1) * HSTRIDE + u] = h;
        __syncthreads();
    }

    // ---- fused G tail from LDS: G[b*100+row][4m..4m+3] = h(row) . W1[:, 4m..4m+3] ----
    const int brow0 = b * TT;
    for (int idx = tid; idx < TT * 13; idx += 256) {
        int row = idx / 13;
        int m = idx - row * 13;
        int j = 4 * m;
        const float* hrow = &h_all[(row + 1) * HSTRIDE];
        float ax = 0.f, ay = 0.f, az = 0.f, aw = 0.f;
#pragma unroll
        for (int u4 = 0; u4 < 16; ++u4) {
            float4 hv = *(const float4*)&hrow[4 * u4];
            float4 w0 = *(const float4*)&w1s[(4 * u4 + 0) * 52 + j];
            float4 w1v = *(const float4*)&w1s[(4 * u4 + 1) * 52 + j];
            float4 w2 = *(const float4*)&w1s[(4 * u4 + 2) * 52 + j];
            float4 w3 = *(const float4*)&w1s[(4 * u4 + 3) * 52 + j];
            ax += hv.x * w0.x + hv.y * w1v.x + hv.z * w2.x + hv.w * w3.x;
            ay += hv.x * w0.y + hv.y * w1v.y + hv.z * w2.y + hv.w * w3.y;
            az += hv.x * w0.z + hv.y * w1v.z + hv.z * w2.z + hv.w * w3.z;
            aw += hv.x * w0.w + hv.y * w1v.w + hv.z * w2.w + hv.w * w3.w;
        }
        if (m == 12) { az = 0.f; aw = 0.f; }  // cols 50,51 (w1s pad garbage) -> 0
        *(float4*)&G[(brow0 + row) * GROW + j] = make_float4(ax, ay, az, aw);
    }
}

// ---------------- K4: suffix-accumulate V[p,j] += a[s,p]*G[s,j]; emit per t-chunk ------
// pro_id row staged in LDS; cos_X gather prefetched 3 iterations deep to hide L2 latency.
__global__ __launch_bounds__(256) void k4_main(const int* __restrict__ pro_id,
    const float* __restrict__ cos_X, const float* __restrict__ XcT,
    const float* __restrict__ G, const float* __restrict__ W2,
    const float* __restrict__ b2, float* __restrict__ out)
{
    __shared__ int spid[TT];
    const int b = blockIdx.z;
    const int p = blockIdx.y * 256 + threadIdx.x;
    const int ci = blockIdx.x;
    const int t0 = ci * 7;
    const int t1 = (t0 + 7 < TT) ? (t0 + 7) : TT;
    const bool valid = p < PP;
    const int pc = valid ? p : 0;

    if (threadIdx.x < TT) spid[threadIdx.x] = pro_id[b * TT + threadIdx.x];

    float V[NJ];
#pragma unroll
    for (int jj = 0; jj < NJ; ++jj) V[jj] = XcT[jj * PP + pc];
    const float b2v = b2[0];
    __syncthreads();

    const float* cb = cos_X + pc;
    float a0 = cb[spid[99] * PP];
    float a1 = (98 >= t0) ? cb[spid[98] * PP] : 0.f;
    float a2 = (97 >= t0) ? cb[spid[97] * PP] : 0.f;

    for (int s = TT - 1; s >= t0; --s) {
        float a = a0; a0 = a1; a1 = a2;
        int sp = s - 3;
        if (sp >= t0) a2 = cb[spid[sp] * PP];
        const float4* G4 = (const float4*)(G + (b * TT + s) * GROW);  // uniform -> SGPR
#pragma unroll
        for (int jv = 0; jv < 13; ++jv) {
            float4 gv = G4[jv];
            V[4 * jv + 0] += a * gv.x;
            V[4 * jv + 1] += a * gv.y;
            V[4 * jv + 2] += a * gv.z;
            V[4 * jv + 3] += a * gv.w;
        }
        if (s < t1) {
            float acc = b2v;
#pragma unroll
            for (int jv = 0; jv < 12; ++jv) {
                float4 wv = *(const float4*)&W2[4 * jv];
                acc += wv.x * fmaxf(V[4 * jv + 0], 0.f)
                     + wv.y * fmaxf(V[4 * jv + 1], 0.f)
                     + wv.z * fmaxf(V[4 * jv + 2], 0.f)
                     + wv.w * fmaxf(V[4 * jv + 3], 0.f);
            }
            acc += W2[48] * fmaxf(V[48], 0.f) + W2[49] * fmaxf(V[49], 0.f);
            if (valid) out[(b * TT + s) * PP + p] = acc;
        }
    }
}

extern "C" void kernel_launch(void* const* d_in, const int* in_sizes, int n_in,
                              void* d_out, int out_size, void* d_ws, size_t ws_size,
                              hipStream_t stream)
{
    const int* pro_id  = (const int*)d_in[0];
    const int* label   = (const int*)d_in[1];
    const float* X     = (const float*)d_in[3];
    const float* cos_X = (const float*)d_in[4];
    // d_in[5] trimatrix: structurally tril(ones) — suffix-sum semantics hardcoded
    const float* onehot = (const float*)d_in[6];
    const float* lk    = (const float*)d_in[7];
    const float* lr    = (const float*)d_in[8];
    const float* lb    = (const float*)d_in[9];
    const float* W1    = (const float*)d_in[10];
    const float* b1    = (const float*)d_in[11];
    const float* W2    = (const float*)d_in[12];
    const float* b2    = (const float*)d_in[13];

    float* ws  = (float*)d_ws;
    float* xk  = ws;            // 204800
    float* XcT = ws + 204800;   // 56000
    float* G   = ws + 260800;   // 44800
    float* out = (float*)d_out;

    hipLaunchKernelGGL(prep,   dim3(116),      dim3(256), 0, stream,
                       pro_id, label, X, onehot, lk, lb, W1, b1, xk, XcT);
    hipLaunchKernelGGL(k2_lstm,dim3(8),        dim3(256), 0, stream, xk, lr, W1, G);
    hipLaunchKernelGGL(k4_main,dim3(15, 4, 8), dim3(256), 0, stream,
                       pro_id, cos_X, XcT, G, W2, b2, out);
}

// Round 6
// 210.163 us; speedup vs baseline: 1.3017x; 1.2591x over previous
//
#include <hip/hip_runtime.h>
#include <math.h>

#define BB 8
#define TT 100
#define PP 1000
#define NJ 52      // V regs per thread in k4 (50 real j, 2 pad)
#define GROW 56    // G row stride floats (224B, 16B aligned)
#define HSTRIDE 68 // h_all row stride floats (272B, 16B aligned)

// ws layout (floats):
//   xk : [800][256] at 0        (204800)
//   XcT: [56][1000] at 204800   (56000)
//   G  : [800][56]  at 260800   (44800)

// ---------------- K1: xk[bt][j] = bias[j] + sum_k xt[bt][k]*kern[k][j] -----------------
// 200 blocks x 4 rows; 8 independent kern loads in flight per k-group (no LDS staging
// of kern -- L2-resident after first touch; round-5 double-buffer gained nothing).
__global__ __launch_bounds__(256) void k1_xk(const int* __restrict__ pro_id,
    const int* __restrict__ label, const float* __restrict__ X,
    const float* __restrict__ onehot, const float* __restrict__ kern,
    const float* __restrict__ bias, float* __restrict__ xk)
{
    __shared__ __align__(16) float xt[4][256];
    const int j = threadIdx.x;
    const int r0 = blockIdx.x * 4;
#pragma unroll
    for (int r = 0; r < 4; ++r) {
        int pid = pro_id[r0 + r];
        int lab = label[r0 + r];
        xt[r][j] = X[pid * 128 + (j & 127)] * onehot[lab * 256 + j];
    }
    __syncthreads();
    float acc[4];
    float bj = bias[j];
#pragma unroll
    for (int r = 0; r < 4; ++r) acc[r] = bj;
#pragma unroll 2
    for (int kg = 0; kg < 32; ++kg) {
        const int k0 = kg * 8;
        float kv[8];
#pragma unroll
        for (int i = 0; i < 8; ++i) kv[i] = kern[(k0 + i) * 256 + j];  // 8 in flight
#pragma unroll
        for (int r = 0; r < 4; ++r) {
            float4 x0 = *(const float4*)&xt[r][k0];      // broadcast LDS
            float4 x1 = *(const float4*)&xt[r][k0 + 4];
            acc[r] += x0.x * kv[0] + x0.y * kv[1] + x0.z * kv[2] + x0.w * kv[3]
                    + x1.x * kv[4] + x1.y * kv[5] + x1.z * kv[6] + x1.w * kv[7];
        }
    }
#pragma unroll
    for (int r = 0; r < 4; ++r) xk[(r0 + r) * 256 + j] = acc[r];
}

// ---------------- MID: blocks 0..7 = LSTM (k2), blocks 8..23 = XcT (k3) ----------------
// k2 and k3 are independent -> run them in ONE launch so k3 hides under the LSTM's
// serial 8-CU phase instead of serializing in the stream.
__global__ __launch_bounds__(256) void mid(const float* __restrict__ xk,
    const float* __restrict__ rec, const float* __restrict__ W1,
    const float* __restrict__ X, const float* __restrict__ b1,
    float* __restrict__ G, float* __restrict__ XcT)
{
    __shared__ __align__(16) float smem[14720];  // 58.9 KB union
    const int tid = threadIdx.x;

    if (blockIdx.x < 8) {
        // ---- LSTM: gate-interleaved lanes, 1 barrier/step, G tail fused ----
        float* h_all = smem;                 // [101][68] = 27.5 KB
        float* w1s   = smem + (TT + 1) * HSTRIDE;  // [64][52] = 13.3 KB
        const int b = blockIdx.x;
        const int l = tid & 63;
        const int w = tid >> 6;
        const int u = (w << 4) | (l & 15);
        const int g = l >> 4;
        const int col = (g << 6) | u;

        for (int idx = tid; idx < 3200; idx += 256) {
            int u2 = idx / 50, jj = idx - u2 * 50;
            w1s[u2 * 52 + jj] = W1[idx];
        }
        float rcol[64];
#pragma unroll
        for (int u2 = 0; u2 < 64; ++u2) rcol[u2] = rec[u2 * 256 + col];

        if (tid < 64) h_all[tid] = 0.f;      // h(-1) = 0
        float c = 0.f;
        const float* xkb = xk + b * TT * 256;
        float zc = xkb[col];                 // prefetch t=0
        __syncthreads();

        for (int t = 0; t < TT; ++t) {
            float a0 = zc, a1 = 0.f, a2 = 0.f, a3 = 0.f;
            int tn = (t + 1 < TT) ? (t + 1) : (TT - 1);
            zc = xkb[tn * 256 + col];        // unconditional clamped prefetch
            const float4* h4p = (const float4*)&h_all[t * HSTRIDE];
#pragma unroll
            for (int m = 0; m < 16; ++m) {
                float4 hv = h4p[m];          // broadcast
                a0 += hv.x * rcol[4 * m + 0];
                a1 += hv.y * rcol[4 * m + 1];
                a2 += hv.z * rcol[4 * m + 2];
                a3 += hv.w * rcol[4 * m + 3];
            }
            float z = (a0 + a1) + (a2 + a3);
            float act;
            if (g == 2) act = 2.f / (1.f + __expf(-2.f * z)) - 1.f;   // tanh gate
            else        act = 1.f / (1.f + __expf(-z));
            const int base = l & 15;
            float gi = __shfl(act, base);
            float gf = __shfl(act, base + 16);
            float gg = __shfl(act, base + 32);
            float go = __shfl(act, base + 48);
            c = gf * c + gi * gg;
            float h = go * (2.f / (1.f + __expf(-2.f * c)) - 1.f);
            if (g == 0) h_all[(t + 1) * HSTRIDE + u] = h;
            __syncthreads();
        }

        const int brow0 = b * TT;
        for (int idx = tid; idx < TT * 13; idx += 256) {
            int row = idx / 13;
            int m = idx - row * 13;
            int j = 4 * m;
            const float* hrow = &h_all[(row + 1) * HSTRIDE];
            float ax = 0.f, ay = 0.f, az = 0.f, aw = 0.f;
#pragma unroll
            for (int u4 = 0; u4 < 16; ++u4) {
                float4 hv  = *(const float4*)&hrow[4 * u4];
                float4 w0  = *(const float4*)&w1s[(4 * u4 + 0) * 52 + j];
                float4 w1v = *(const float4*)&w1s[(4 * u4 + 1) * 52 + j];
                float4 w2  = *(const float4*)&w1s[(4 * u4 + 2) * 52 + j];
                float4 w3  = *(const float4*)&w1s[(4 * u4 + 3) * 52 + j];
                ax += hv.x * w0.x + hv.y * w1v.x + hv.z * w2.x + hv.w * w3.x;
                ay += hv.x * w0.y + hv.y * w1v.y + hv.z * w2.y + hv.w * w3.y;
                az += hv.x * w0.z + hv.y * w1v.z + hv.z * w2.z + hv.w * w3.z;
                aw += hv.x * w0.w + hv.y * w1v.w + hv.z * w2.w + hv.w * w3.w;
            }
            if (m == 12) { az = 0.f; aw = 0.f; }   // cols 50,51 = 0
            *(float4*)&G[(brow0 + row) * GROW + j] = make_float4(ax, ay, az, aw);
        }
    } else {
        // ---- k3: XcT[j][p] = b1[j] + sum_k X[p][k]*W1[64+k][j] ----
        float* Xs  = smem;          // [128][65] = 33.3 KB
        float* W1T = smem + 8320;   // [50][128] = 25.6 KB
        const int p0 = (blockIdx.x - 8) * 64;
        for (int idx = tid; idx < 6400; idx += 256) {
            int k = idx & 127, jj = idx >> 7;
            W1T[jj * 128 + k] = W1[(64 + k) * 50 + jj];
        }
#pragma unroll
        for (int r = 0; r < 8; ++r) {
            int flat = (tid + 256 * r) * 4;
            int i = flat >> 7;
            int k = flat & 127;
            int p = p0 + i;
            float4 v = make_float4(0.f, 0.f, 0.f, 0.f);
            if (p < PP) v = *(const float4*)&X[p * 128 + k];
            Xs[(k + 0) * 65 + i] = v.x;
            Xs[(k + 1) * 65 + i] = v.y;
            Xs[(k + 2) * 65 + i] = v.z;
            Xs[(k + 3) * 65 + i] = v.w;
        }
        __syncthreads();
        const int ploc = tid & 63;
        const int j0 = tid >> 6;
        float acc[13];
#pragma unroll
        for (int m = 0; m < 13; ++m) {
            int jj = j0 * 13 + m;
            acc[m] = (jj < 50) ? b1[jj] : 0.f;
        }
        for (int k4 = 0; k4 < 32; ++k4) {
            const int k = 4 * k4;
            float x0 = Xs[(k + 0) * 65 + ploc];
            float x1 = Xs[(k + 1) * 65 + ploc];
            float x2 = Xs[(k + 2) * 65 + ploc];
            float x3 = Xs[(k + 3) * 65 + ploc];
#pragma unroll
            for (int m = 0; m < 13; ++m) {
                int jj = j0 * 13 + m;
                if (jj < 50) {
                    float4 w = *(const float4*)&W1T[jj * 128 + k];
                    acc[m] += x0 * w.x + x1 * w.y + x2 * w.z + x3 * w.w;
                }
            }
        }
        int p = p0 + ploc;
        if (p < PP) {
#pragma unroll
            for (int m = 0; m < 13; ++m) {
                int jj = j0 * 13 + m;
                if (jj < 50) XcT[jj * PP + p] = acc[m];
            }
        }
        for (int idx = tid; idx < 6 * 64; idx += 256) {
            int r = 50 + (idx >> 6);
            int pp = p0 + (idx & 63);
            if (pp < PP) XcT[r * PP + pp] = 0.f;
        }
    }
}

// ---------------- K4: suffix-accumulate V[p,j] += a[s,p]*Gs[s,j]; emit per t-chunk -----
// G slab for batch b staged in LDS (22.4 KB, contiguous, once per block) -> in-loop G
// reads are broadcast ds_read_b128 (round-5 did 13 global L2 loads/iter -> 2060 cyc/iter).
// cos_X prefetch depth 4, unconditional clamped index (no branch).
__global__ __launch_bounds__(256) void k4_main(const int* __restrict__ pro_id,
    const float* __restrict__ cos_X, const float* __restrict__ XcT,
    const float* __restrict__ G, const float* __restrict__ W2,
    const float* __restrict__ b2, float* __restrict__ out)
{
    __shared__ __align__(16) float Gs[TT * GROW];  // 22.4 KB
    __shared__ float w2s[NJ];
    __shared__ int spid[TT];
    const int b = blockIdx.z;
    const int p = blockIdx.y * 256 + threadIdx.x;
    const int ci = blockIdx.x;
    const int t0 = ci * 7;
    const int t1 = (t0 + 7 < TT) ? (t0 + 7) : TT;
    const bool valid = p < PP;
    const int pc = valid ? p : 0;
    const int tid = threadIdx.x;

    // stage G slab (contiguous floats [b*5600, b*5600+5600)), spid row, W2
    {
        const float4* Gg = (const float4*)(G + b * TT * GROW);
        float4* Gd = (float4*)Gs;
        for (int idx = tid; idx < TT * GROW / 4; idx += 256) Gd[idx] = Gg[idx];
        if (tid < TT) spid[tid] = pro_id[b * TT + tid];
        if (tid < NJ) w2s[tid] = (tid < 50) ? W2[tid] : 0.f;
    }

    float V[NJ];
#pragma unroll
    for (int jj = 0; jj < NJ; ++jj) V[jj] = XcT[jj * PP + pc];
    const float b2v = b2[0];
    __syncthreads();

    const float* cb = cos_X + pc;
    float a0 = cb[spid[99] * PP];
    float a1 = cb[spid[98] * PP];
    float a2 = cb[spid[97] * PP];
    float a3 = cb[spid[96] * PP];

    for (int s = TT - 1; s >= t0; --s) {
        float a = a0; a0 = a1; a1 = a2; a2 = a3;
        int sp = s - 4;
        if (sp < t0) sp = t0;                 // clamp -> unconditional load
        a3 = cb[spid[sp] * PP];
        const float4* G4 = (const float4*)&Gs[s * GROW];   // broadcast LDS
#pragma unroll
        for (int jv = 0; jv < 13; ++jv) {
            float4 gv = G4[jv];
            V[4 * jv + 0] += a * gv.x;
            V[4 * jv + 1] += a * gv.y;
            V[4 * jv + 2] += a * gv.z;
            V[4 * jv + 3] += a * gv.w;
        }
        if (s < t1) {
            float acc = b2v;
#pragma unroll
            for (int jv = 0; jv < 13; ++jv) {
                float4 wv = *(const float4*)&w2s[4 * jv];  // w2s[50,51]=0
                acc += wv.x * fmaxf(V[4 * jv + 0], 0.f)
                     + wv.y * fmaxf(V[4 * jv + 1], 0.f)
                     + wv.z * fmaxf(V[4 * jv + 2], 0.f)
                     + wv.w * fmaxf(V[4 * jv + 3], 0.f);
            }
            if (valid) out[(b * TT + s) * PP + p] = acc;
        }
    }
}

extern "C" void kernel_launch(void* const* d_in, const int* in_sizes, int n_in,
                              void* d_out, int out_size, void* d_ws, size_t ws_size,
                              hipStream_t stream)
{
    const int* pro_id  = (const int*)d_in[0];
    const int* label   = (const int*)d_in[1];
    const float* X     = (const float*)d_in[3];
    const float* cos_X = (const float*)d_in[4];
    // d_in[5] trimatrix: structurally tril(ones) — suffix-sum semantics hardcoded
    const float* onehot = (const float*)d_in[6];
    const float* lk    = (const float*)d_in[7];
    const float* lr    = (const float*)d_in[8];
    const float* lb    = (const float*)d_in[9];
    const float* W1    = (const float*)d_in[10];
    const float* b1    = (const float*)d_in[11];
    const float* W2    = (const float*)d_in[12];
    const float* b2    = (const float*)d_in[13];

    float* ws  = (float*)d_ws;
    float* xk  = ws;            // 204800
    float* XcT = ws + 204800;   // 56000
    float* G   = ws + 260800;   // 44800
    float* out = (float*)d_out;

    hipLaunchKernelGGL(k1_xk,  dim3(200),      dim3(256), 0, stream,
                       pro_id, label, X, onehot, lk, lb, xk);
    hipLaunchKernelGGL(mid,    dim3(24),       dim3(256), 0, stream,
                       xk, lr, W1, X, b1, G, XcT);
    hipLaunchKernelGGL(k4_main,dim3(15, 4, 8), dim3(256), 0, stream,
                       pro_id, cos_X, XcT, G, W2, b2, out);
}